// Round 1
// baseline (166.807 us; speedup 1.0000x reference)
//
#include <hip/hip_runtime.h>
#include <math.h>

#define NUM_K 16
#define FD 4
#define DELTA_V 0.5f
#define DELTA_D 1.5f

// ws layout (floats):
//   cntk [B*16]      @ 0
//   sumk [B*16*4]    @ 128
//   vsum [B*16]      @ 640
//   vcnt [B*16]      @ 768
// total 896 floats = 3584 bytes (zeroed via hipMemsetAsync each launch)

__global__ __launch_bounds__(256) void pass1_kernel(
    const float* __restrict__ emb, const int* __restrict__ inst,
    const float* __restrict__ kern, const float* __restrict__ tmask,
    float* __restrict__ cntk, float* __restrict__ sumk, int N)
{
    const int b = blockIdx.y;
    __shared__ float s_cnt[NUM_K];
    __shared__ float s_sum[NUM_K][FD];

    for (int i = threadIdx.x; i < NUM_K; i += blockDim.x) {
        s_cnt[i] = 0.f;
        #pragma unroll
        for (int d = 0; d < FD; ++d) s_sum[i][d] = 0.f;
    }
    __syncthreads();

    const size_t base = (size_t)b * N;
    const int4*   iv4 = (const int4*)(inst + base);
    const float4* kv4 = (const float4*)(kern + base);
    const float4* tv4 = (const float4*)(tmask + base);
    const float4* e0v = (const float4*)(emb + ((size_t)b * FD + 0) * N);
    const float4* e1v = (const float4*)(emb + ((size_t)b * FD + 1) * N);
    const float4* e2v = (const float4*)(emb + ((size_t)b * FD + 2) * N);
    const float4* e3v = (const float4*)(emb + ((size_t)b * FD + 3) * N);

    const int ng = N >> 2;
    for (int g = blockIdx.x * blockDim.x + threadIdx.x; g < ng;
         g += gridDim.x * blockDim.x) {
        int4   iv = iv4[g];
        float4 kv = kv4[g];
        float4 tv = tv4[g];
        float4 a0 = e0v[g], a1 = e1v[g], a2 = e2v[g], a3 = e3v[g];

        #define ACC(px)                                                        \
            {                                                                  \
                int lab = (tv.px > 0.5f) ? iv.px : 0;                          \
                if (lab > 0 && kv.px > 0.5f) {                                 \
                    atomicAdd(&s_cnt[lab], 1.f);                               \
                    atomicAdd(&s_sum[lab][0], a0.px);                          \
                    atomicAdd(&s_sum[lab][1], a1.px);                          \
                    atomicAdd(&s_sum[lab][2], a2.px);                          \
                    atomicAdd(&s_sum[lab][3], a3.px);                          \
                }                                                              \
            }
        ACC(x) ACC(y) ACC(z) ACC(w)
        #undef ACC
    }
    __syncthreads();

    for (int i = threadIdx.x; i < NUM_K; i += blockDim.x) {
        if (s_cnt[i] != 0.f) {
            atomicAdd(&cntk[b * NUM_K + i], s_cnt[i]);
            #pragma unroll
            for (int d = 0; d < FD; ++d)
                atomicAdd(&sumk[(b * NUM_K + i) * FD + d], s_sum[i][d]);
        }
    }
}

__global__ __launch_bounds__(256) void pass2_kernel(
    const float* __restrict__ emb, const int* __restrict__ inst,
    const float* __restrict__ tmask,
    const float* __restrict__ cntk, const float* __restrict__ sumk,
    float* __restrict__ vsum, float* __restrict__ vcnt, int N)
{
    const int b = blockIdx.y;
    __shared__ float s_mean[NUM_K][FD];
    __shared__ float s_vs[NUM_K];
    __shared__ float s_vc[NUM_K];

    if (threadIdx.x < NUM_K * FD) {
        int k = threadIdx.x >> 2, d = threadIdx.x & 3;
        float c = cntk[b * NUM_K + k];
        float m = (k == 0) ? 0.f
                           : sumk[(b * NUM_K + k) * FD + d] / fmaxf(c, 1.f);
        s_mean[k][d] = m;
    }
    if (threadIdx.x < NUM_K) { s_vs[threadIdx.x] = 0.f; s_vc[threadIdx.x] = 0.f; }
    __syncthreads();

    const size_t base = (size_t)b * N;
    const int4*   iv4 = (const int4*)(inst + base);
    const float4* tv4 = (const float4*)(tmask + base);
    const float4* e0v = (const float4*)(emb + ((size_t)b * FD + 0) * N);
    const float4* e1v = (const float4*)(emb + ((size_t)b * FD + 1) * N);
    const float4* e2v = (const float4*)(emb + ((size_t)b * FD + 2) * N);
    const float4* e3v = (const float4*)(emb + ((size_t)b * FD + 3) * N);

    const int ng = N >> 2;
    for (int g = blockIdx.x * blockDim.x + threadIdx.x; g < ng;
         g += gridDim.x * blockDim.x) {
        int4   iv = iv4[g];
        float4 tv = tv4[g];
        float4 a0 = e0v[g], a1 = e1v[g], a2 = e2v[g], a3 = e3v[g];

        #define DIST(px)                                                       \
            {                                                                  \
                int lab = (tv.px > 0.5f) ? iv.px : 0;                          \
                if (lab > 0) {                                                 \
                    float dx = a0.px - s_mean[lab][0];                         \
                    float dy = a1.px - s_mean[lab][1];                         \
                    float dz = a2.px - s_mean[lab][2];                         \
                    float dw = a3.px - s_mean[lab][3];                         \
                    float dist = sqrtf(dx*dx + dy*dy + dz*dz + dw*dw);         \
                    float r = fmaxf(dist - DELTA_V, 0.f);                      \
                    float val = logf(r * r + 1.f);                             \
                    atomicAdd(&s_vs[lab], val);                                \
                    atomicAdd(&s_vc[lab], 1.f);                                \
                }                                                              \
            }
        DIST(x) DIST(y) DIST(z) DIST(w)
        #undef DIST
    }
    __syncthreads();

    for (int i = threadIdx.x; i < NUM_K; i += blockDim.x) {
        if (s_vc[i] != 0.f) {
            atomicAdd(&vsum[b * NUM_K + i], s_vs[i]);
            atomicAdd(&vcnt[b * NUM_K + i], s_vc[i]);
        }
    }
}

__global__ __launch_bounds__(128) void finalize_kernel(
    const float* __restrict__ cntk, const float* __restrict__ sumk,
    const float* __restrict__ vsum, const float* __restrict__ vcnt,
    float* __restrict__ out, int B)
{
    __shared__ float s_mean[8][NUM_K][FD];
    __shared__ float s_part[128];

    const int t = threadIdx.x;          // 0..127 = B*K
    const int b = t >> 4;
    const int k = t & 15;

    float c = cntk[t];
    float m0 = 0.f, m1 = 0.f, m2 = 0.f, m3 = 0.f;
    if (k != 0) {
        float inv = 1.f / fmaxf(c, 1.f);
        m0 = sumk[t * FD + 0] * inv;
        m1 = sumk[t * FD + 1] * inv;
        m2 = sumk[t * FD + 2] * inv;
        m3 = sumk[t * FD + 3] * inv;
    }
    s_mean[b][k][0] = m0; s_mean[b][k][1] = m1;
    s_mean[b][k][2] = m2; s_mean[b][k][3] = m3;
    __syncthreads();

    float partial = 0.f;

    // l_agg contribution: mean(agg[1:]) over 15 labels
    if (k >= 1) {
        float agg = vsum[t] / fmaxf(vcnt[t], 1.f);
        partial += agg / 15.f;
    }

    // l_dis contribution: pairwise, excluding diag and label 0
    if (k >= 1) {
        #pragma unroll
        for (int j = 1; j < NUM_K; ++j) {
            if (j == k) continue;
            float dx = m0 - s_mean[b][j][0];
            float dy = m1 - s_mean[b][j][1];
            float dz = m2 - s_mean[b][j][2];
            float dw = m3 - s_mean[b][j][3];
            float sq = dx*dx + dy*dy + dz*dz + dw*dw;
            float pd = sqrtf(sq);
            float r = fmaxf(2.f * DELTA_D - pd, 0.f);
            partial += logf(r * r + 1.f) / 210.f;   // (K-1)*(K-2)
        }
    }

    // l_reg: mean over all 16 labels of log(||mean||+1) * 0.001
    {
        float nrm = sqrtf(m0*m0 + m1*m1 + m2*m2 + m3*m3);
        partial += logf(nrm + 1.f) * (0.001f / 16.f);
    }

    s_part[t] = partial;
    __syncthreads();

    if (t == 0) {
        float s = 0.f;
        for (int i = 0; i < 128; ++i) s += s_part[i];
        out[0] = s / (float)B;
    }
}

extern "C" void kernel_launch(void* const* d_in, const int* in_sizes, int n_in,
                              void* d_out, int out_size, void* d_ws, size_t ws_size,
                              hipStream_t stream) {
    const float* emb   = (const float*)d_in[0];
    const int*   inst  = (const int*)d_in[1];
    const float* kern  = (const float*)d_in[2];
    const float* tmask = (const float*)d_in[3];
    // d_in[4] = bboxes, unused

    const int B = 8;
    const int N = in_sizes[1] / B;      // 640*640

    float* ws   = (float*)d_ws;
    float* cntk = ws;                   // B*16
    float* sumk = ws + 128;             // B*16*4
    float* vsum = ws + 640;             // B*16
    float* vcnt = ws + 768;             // B*16
    float* outf = (float*)d_out;

    hipMemsetAsync(d_ws, 0, 896 * sizeof(float), stream);

    dim3 blk(256);
    dim3 grd(128, B);
    pass1_kernel<<<grd, blk, 0, stream>>>(emb, inst, kern, tmask, cntk, sumk, N);
    pass2_kernel<<<grd, blk, 0, stream>>>(emb, inst, tmask, cntk, sumk, vsum, vcnt, N);
    finalize_kernel<<<dim3(1), dim3(128), 0, stream>>>(cntk, sumk, vsum, vcnt, outf, B);
}